// Round 5
// baseline (330.690 us; speedup 1.0000x reference)
//
#include <hip/hip_runtime.h>
#include <hip/hip_bf16.h>
#include <math.h>

#define DIM 256
#define NHEAD 8
#define HD 32
#define WH 5
#define WW 2
#define NTOK 10
#define WPAT 64
#define LTOK 5120
#define NTOKEN 163840
#define EPS 1e-5f

typedef __attribute__((ext_vector_type(8))) short bh8;
typedef __attribute__((ext_vector_type(4))) short sh4;
typedef __attribute__((ext_vector_type(4))) float fx4;

__device__ inline unsigned short f2bf(float f) {
    unsigned int u = __builtin_bit_cast(unsigned int, f);
    u += 0x7fffu + ((u >> 16) & 1u);
    return (unsigned short)(u >> 16);
}
__device__ inline float bf2f(unsigned short h) {
    return __builtin_bit_cast(float, (unsigned int)h << 16);
}

__device__ inline float wave_reduce_sum(float v) {
    #pragma unroll
    for (int off = 32; off > 0; off >>= 1) v += __shfl_xor(v, off);
    return v;
}

// ---- kernel 0: weight prep. f32 [K][N] -> bf16 MFMA-fragment order:
//      wtf[((mat*4+s)*4+ni)*8+ko][lane][j] = W[ko*32+(lane>>4)*8+j][s*64+ni*16+(lane&15)]
__global__ void prep_kernel(const float* __restrict__ w1,
                            const float* __restrict__ w2,
                            unsigned short* __restrict__ wtf) {
    int gid = blockIdx.x * 256 + threadIdx.x;   // 16384 threads, 8 shorts each
    int lane = gid & 63;
    int ko = (gid >> 6) & 7;
    int ni = (gid >> 9) & 3;
    int s  = (gid >> 11) & 3;
    int mat = gid >> 13;
    const float* src = mat ? w2 : w1;
    int col = s * 64 + ni * 16 + (lane & 15);
    int k0 = ko * 32 + (lane >> 4) * 8;
    unsigned short* dst = wtf + (size_t)gid * 8;
    #pragma unroll
    for (int j = 0; j < 8; ++j)
        dst[j] = f2bf(src[(k0 + j) * 256 + col]);
}

// ---------------- kernel 1: LN1 + window attention + residual -> x1 -----------------
// BF=1: write bf16 to x1h (workspace). BF=0: write f32 to x1f (d_out).
template<int BF>
__global__ __launch_bounds__(256) void attn_kernel(
    const float* __restrict__ x, const float* __restrict__ g1,
    const float* __restrict__ b1, const float* __restrict__ btab,
    float* __restrict__ x1f, unsigned short* __restrict__ x1h) {
    __shared__ float xs[NTOK][DIM + 8];
    __shared__ float hs[NTOK][DIM + 8];
    __shared__ float pm[NHEAD * NTOK * NTOK];

    int w = blockIdx.x;              // 0..16383
    int b = w >> 9;
    int rh = (w >> 5) & 15;
    int cw = w & 31;
    int tid = threadIdx.x;
    int lane = tid & 63;
    int wave = tid >> 6;
    long base = (long)b * LTOK + rh * (WH * WPAT) + cw * WW;

    #pragma unroll
    for (int i = 0; i < WH; ++i) {
        const float2* src = (const float2*)(x + (base + (long)i * WPAT) * DIM);
        float2 v = src[tid];
        int p = tid * 2;
        int tok = i * 2 + (p >> 8);
        int c = p & 255;
        *(float2*)&xs[tok][c] = v;
    }
    __syncthreads();

    float4 g4 = *(const float4*)(g1 + lane * 4);
    float4 b4 = *(const float4*)(b1 + lane * 4);
    for (int tok = wave; tok < NTOK; tok += 4) {
        float4 v = *(const float4*)&xs[tok][lane * 4];
        float s = v.x + v.y + v.z + v.w;
        float q = v.x * v.x + v.y * v.y + v.z * v.z + v.w * v.w;
        s = wave_reduce_sum(s);
        q = wave_reduce_sum(q);
        float mean = s * (1.0f / DIM);
        float var = q * (1.0f / DIM) - mean * mean;
        float rstd = rsqrtf(var + EPS);
        float4 h;
        h.x = (v.x - mean) * rstd * g4.x + b4.x;
        h.y = (v.y - mean) * rstd * g4.y + b4.y;
        h.z = (v.z - mean) * rstd * g4.z + b4.z;
        h.w = (v.w - mean) * rstd * g4.w + b4.w;
        *(float4*)&hs[tok][lane * 4] = h;
    }
    __syncthreads();

    const float scale = 0.17677669529663689f;   // 32^-0.5
    for (int item = tid; item < NHEAD * NTOK * NTOK; item += 256) {
        int head = item / 100;
        int rem = item - head * 100;
        int q = rem / 10;
        int k = rem - q * 10;
        float acc = 0.f;
        #pragma unroll
        for (int d = 0; d < HD; ++d)
            acc += hs[q][head * HD + d] * hs[k][head * HD + d];
        int iq = q >> 1, jq = q & 1, ik = k >> 1, jk = k & 1;
        int bidx = (iq - ik + WH - 1) * (2 * WW - 1) + (jq - jk + WW - 1);
        pm[item] = acc * scale + btab[bidx * NHEAD + head];
    }
    __syncthreads();

    if (tid < NHEAD * NTOK) {
        float* row = pm + tid * NTOK;
        float m = row[0];
        #pragma unroll
        for (int k = 1; k < NTOK; ++k) m = fmaxf(m, row[k]);
        float e[NTOK];
        float s = 0.f;
        #pragma unroll
        for (int k = 0; k < NTOK; ++k) { e[k] = __expf(row[k] - m); s += e[k]; }
        float inv = 1.0f / s;
        #pragma unroll
        for (int k = 0; k < NTOK; ++k) row[k] = e[k] * inv;
    }
    __syncthreads();

    int head = tid >> 5;
    float hv[NTOK];
    #pragma unroll
    for (int k = 0; k < NTOK; ++k) hv[k] = hs[k][tid];
    #pragma unroll
    for (int q = 0; q < NTOK; ++q) {
        const float* pr = pm + (head * NTOK + q) * NTOK;
        float acc = 0.f;
        #pragma unroll
        for (int k = 0; k < NTOK; ++k) acc += pr[k] * hv[k];
        float o = xs[q][tid] + acc;
        long l = base + (q >> 1) * WPAT + (q & 1);
        if (BF) x1h[l * DIM + tid] = f2bf(o);
        else    x1f[l * DIM + tid] = o;
    }
}

// ---------------- kernel 2 (main): bf16 x1 in ws -> LN2 + MLP -> f32 d_out ----------
// __launch_bounds__(256,4): cap VGPR at 128 so 4 blocks/CU stay resident (LDS cap).
__global__ __launch_bounds__(256, 4) void mlp_bf_kernel(
    const unsigned short* __restrict__ x1h, float* __restrict__ out,
    const float* __restrict__ g2, const float* __restrict__ b2,
    const unsigned short* __restrict__ wtf,
    const float* __restrict__ mb1, const float* __restrict__ mb2) {
    __shared__ unsigned short As[64][DIM + 8];

    int m0 = blockIdx.x * 64;
    int tid = threadIdx.x;
    int lane = tid & 63;
    int wave = tid >> 6;
    int lr = lane & 15;
    int lk = lane >> 4;
    int n0 = wave * 64;

    const unsigned short* w1base = wtf + (size_t)wave * 16384 + (size_t)lane * 8;
    const unsigned short* w2base = wtf + 65536 + (size_t)wave * 16384 + (size_t)lane * 8;

    int r = tid >> 2;          // row 0..63
    int q = tid & 3;           // 64-ch segment 0..3
    const bh8* rowp = (const bh8*)(x1h + (size_t)(m0 + r) * DIM + q * 64);

    // ---- LN2: load bf16 segment (dies after this phase), weight burst overlaps
    {
        bh8 xv[8];
        #pragma unroll
        for (int j = 0; j < 8; ++j) xv[j] = rowp[j];

        float s = 0.f, sq = 0.f;
        #pragma unroll
        for (int j = 0; j < 8; ++j)
            #pragma unroll
            for (int e = 0; e < 8; ++e) {
                float f = bf2f((unsigned short)xv[j][e]);
                s += f; sq += f * f;
            }
        s += __shfl_xor(s, 1);  s += __shfl_xor(s, 2);
        sq += __shfl_xor(sq, 1); sq += __shfl_xor(sq, 2);
        float mean = s * (1.0f / DIM);
        float var = sq * (1.0f / DIM) - mean * mean;
        float rstd = rsqrtf(var + EPS);

        const float4* g4p = (const float4*)g2;
        const float4* b4p = (const float4*)b2;
        #pragma unroll
        for (int j = 0; j < 8; ++j) {
            int c4 = q * 16 + j * 2;
            float4 gA = g4p[c4],     bA = b4p[c4];
            float4 gB = g4p[c4 + 1], bB = b4p[c4 + 1];
            bh8 h;
            h[0] = (short)f2bf((bf2f((unsigned short)xv[j][0]) - mean) * rstd * gA.x + bA.x);
            h[1] = (short)f2bf((bf2f((unsigned short)xv[j][1]) - mean) * rstd * gA.y + bA.y);
            h[2] = (short)f2bf((bf2f((unsigned short)xv[j][2]) - mean) * rstd * gA.z + bA.z);
            h[3] = (short)f2bf((bf2f((unsigned short)xv[j][3]) - mean) * rstd * gA.w + bA.w);
            h[4] = (short)f2bf((bf2f((unsigned short)xv[j][4]) - mean) * rstd * gB.x + bB.x);
            h[5] = (short)f2bf((bf2f((unsigned short)xv[j][5]) - mean) * rstd * gB.y + bB.y);
            h[6] = (short)f2bf((bf2f((unsigned short)xv[j][6]) - mean) * rstd * gB.z + bB.z);
            h[7] = (short)f2bf((bf2f((unsigned short)xv[j][7]) - mean) * rstd * gB.w + bB.w);
            *(bh8*)&As[r][q * 64 + j * 8] = h;
        }
    }

    // GEMM1 weight burst (32 coalesced dwordx4, independent)
    bh8 wf[4][8];
    #pragma unroll
    for (int ni = 0; ni < 4; ++ni)
        #pragma unroll
        for (int ko = 0; ko < 8; ++ko)
            wf[ni][ko] = *(const bh8*)(w1base + (size_t)(ni * 8 + ko) * 512);

    float bias1v[4];
    #pragma unroll
    for (int ni = 0; ni < 4; ++ni) bias1v[ni] = mb1[n0 + ni * 16 + lr];
    __syncthreads();

    const fx4 zero = {0.f, 0.f, 0.f, 0.f};

    // ---- GEMM1 (one A-fragment live per mi step)
    fx4 acc[4][4];
    #pragma unroll
    for (int mi = 0; mi < 4; ++mi)
        #pragma unroll
        for (int ni = 0; ni < 4; ++ni) acc[mi][ni] = zero;

    #pragma unroll
    for (int ko = 0; ko < 8; ++ko) {
        #pragma unroll
        for (int mi = 0; mi < 4; ++mi) {
            bh8 a = *(const bh8*)&As[mi * 16 + lr][ko * 32 + lk * 8];
            #pragma unroll
            for (int ni = 0; ni < 4; ++ni)
                acc[mi][ni] = __builtin_amdgcn_mfma_f32_16x16x32_bf16(a, wf[ni][ko], acc[mi][ni], 0, 0, 0);
        }
    }
    __syncthreads();

    // GEMM2 weight burst; hides under gelu VALU
    #pragma unroll
    for (int ni = 0; ni < 4; ++ni)
        #pragma unroll
        for (int ko = 0; ko < 8; ++ko)
            wf[ni][ko] = *(const bh8*)(w2base + (size_t)(ni * 8 + ko) * 512);

    float bias2v[4];
    #pragma unroll
    for (int ni = 0; ni < 4; ++ni) bias2v[ni] = mb2[n0 + ni * 16 + lr];

    // ---- bias1 + gelu -> bf16 back into As
    #pragma unroll
    for (int mi = 0; mi < 4; ++mi)
        #pragma unroll
        for (int ni = 0; ni < 4; ++ni)
            #pragma unroll
            for (int rr = 0; rr < 4; ++rr) {
                float vv = acc[mi][ni][rr] + bias1v[ni];
                float t = 0.7978845608028654f * (vv + 0.044715f * vv * vv * vv);
                float ge = vv / (1.0f + __expf(-2.0f * t));
                As[mi * 16 + lk * 4 + rr][n0 + ni * 16 + lr] = f2bf(ge);
            }
    __syncthreads();

    // ---- GEMM2
    fx4 acc2[4][4];
    #pragma unroll
    for (int mi = 0; mi < 4; ++mi)
        #pragma unroll
        for (int ni = 0; ni < 4; ++ni) acc2[mi][ni] = zero;

    #pragma unroll
    for (int ko = 0; ko < 8; ++ko) {
        #pragma unroll
        for (int mi = 0; mi < 4; ++mi) {
            bh8 a = *(const bh8*)&As[mi * 16 + lr][ko * 32 + lk * 8];
            #pragma unroll
            for (int ni = 0; ni < 4; ++ni)
                acc2[mi][ni] = __builtin_amdgcn_mfma_f32_16x16x32_bf16(a, wf[ni][ko], acc2[mi][ni], 0, 0, 0);
        }
    }
    __syncthreads();

    // ---- stash bias2-added mlp output (bf16) in As for the coalesced epilogue
    #pragma unroll
    for (int mi = 0; mi < 4; ++mi)
        #pragma unroll
        for (int ni = 0; ni < 4; ++ni)
            #pragma unroll
            for (int rr = 0; rr < 4; ++rr)
                As[mi * 16 + lk * 4 + rr][n0 + ni * 16 + lr] = f2bf(acc2[mi][ni][rr] + bias2v[ni]);
    __syncthreads();

    // ---- epilogue: re-read x1 segment (L2-hot) + mlp_out from LDS, float4 stores
    bh8 xv[8];
    #pragma unroll
    for (int j = 0; j < 8; ++j) xv[j] = rowp[j];

    float* orow = out + (size_t)(m0 + r) * DIM + q * 64;
    #pragma unroll
    for (int j = 0; j < 8; ++j) {
        bh8 mv = *(const bh8*)&As[r][q * 64 + j * 8];
        float4 o0, o1;
        o0.x = bf2f((unsigned short)xv[j][0]) + bf2f((unsigned short)mv[0]);
        o0.y = bf2f((unsigned short)xv[j][1]) + bf2f((unsigned short)mv[1]);
        o0.z = bf2f((unsigned short)xv[j][2]) + bf2f((unsigned short)mv[2]);
        o0.w = bf2f((unsigned short)xv[j][3]) + bf2f((unsigned short)mv[3]);
        o1.x = bf2f((unsigned short)xv[j][4]) + bf2f((unsigned short)mv[4]);
        o1.y = bf2f((unsigned short)xv[j][5]) + bf2f((unsigned short)mv[5]);
        o1.z = bf2f((unsigned short)xv[j][6]) + bf2f((unsigned short)mv[6]);
        o1.w = bf2f((unsigned short)xv[j][7]) + bf2f((unsigned short)mv[7]);
        *(float4*)(orow + j * 8)     = o0;
        *(float4*)(orow + j * 8 + 4) = o1;
    }
}

// ---------------- kernel 2 (fallback): round-3 in-place f32 path --------------------
__global__ __launch_bounds__(256, 2) void mlp_kernel(
    float* __restrict__ xio,
    const float* __restrict__ g2, const float* __restrict__ b2,
    const unsigned short* __restrict__ wtf,
    const float* __restrict__ mb1, const float* __restrict__ mb2) {
    __shared__ unsigned short As[64][DIM + 8];

    int m0 = blockIdx.x * 64;
    int tid = threadIdx.x;
    int lane = tid & 63;
    int wave = tid >> 6;
    int lr = lane & 15;
    int lk = lane >> 4;
    int n0 = wave * 64;

    const unsigned short* w1base = wtf + (size_t)wave * 16384 + (size_t)lane * 8;
    const unsigned short* w2base = wtf + 65536 + (size_t)wave * 16384 + (size_t)lane * 8;

    int r = tid >> 2;
    int q = tid & 3;
    const float4* rowp = (const float4*)(xio + (long)(m0 + r) * DIM);
    float4 v[16];
    #pragma unroll
    for (int i = 0; i < 16; ++i) v[i] = rowp[q + 4 * i];

    bh8 wf[4][8];
    #pragma unroll
    for (int ni = 0; ni < 4; ++ni)
        #pragma unroll
        for (int ko = 0; ko < 8; ++ko)
            wf[ni][ko] = *(const bh8*)(w1base + (size_t)(ni * 8 + ko) * 512);

    float bias1v[4];
    #pragma unroll
    for (int ni = 0; ni < 4; ++ni) bias1v[ni] = mb1[n0 + ni * 16 + lr];

    {
        float s = 0.f, sq = 0.f;
        #pragma unroll
        for (int i = 0; i < 16; ++i) {
            s += v[i].x + v[i].y + v[i].z + v[i].w;
            sq += v[i].x * v[i].x + v[i].y * v[i].y + v[i].z * v[i].z + v[i].w * v[i].w;
        }
        s += __shfl_xor(s, 1);  s += __shfl_xor(s, 2);
        sq += __shfl_xor(sq, 1); sq += __shfl_xor(sq, 2);
        float mean = s * (1.0f / DIM);
        float var = sq * (1.0f / DIM) - mean * mean;
        float rstd = rsqrtf(var + EPS);

        const float4* g4p = (const float4*)g2;
        const float4* b4p = (const float4*)b2;
        #pragma unroll
        for (int i = 0; i < 16; ++i) {
            int c4 = q + 4 * i;
            float4 gg = g4p[c4];
            float4 bb = b4p[c4];
            sh4 h;
            h.x = (short)f2bf((v[i].x - mean) * rstd * gg.x + bb.x);
            h.y = (short)f2bf((v[i].y - mean) * rstd * gg.y + bb.y);
            h.z = (short)f2bf((v[i].z - mean) * rstd * gg.z + bb.z);
            h.w = (short)f2bf((v[i].w - mean) * rstd * gg.w + bb.w);
            *(sh4*)&As[r][c4 * 4] = h;
        }
    }
    __syncthreads();

    const fx4 zero = {0.f, 0.f, 0.f, 0.f};

    fx4 acc[4][4];
    #pragma unroll
    for (int mi = 0; mi < 4; ++mi)
        #pragma unroll
        for (int ni = 0; ni < 4; ++ni) acc[mi][ni] = zero;

    #pragma unroll
    for (int ko = 0; ko < 8; ++ko) {
        #pragma unroll
        for (int mi = 0; mi < 4; ++mi) {
            bh8 a = *(const bh8*)&As[mi * 16 + lr][ko * 32 + lk * 8];
            #pragma unroll
            for (int ni = 0; ni < 4; ++ni)
                acc[mi][ni] = __builtin_amdgcn_mfma_f32_16x16x32_bf16(a, wf[ni][ko], acc[mi][ni], 0, 0, 0);
        }
    }
    __syncthreads();

    #pragma unroll
    for (int ni = 0; ni < 4; ++ni)
        #pragma unroll
        for (int ko = 0; ko < 8; ++ko)
            wf[ni][ko] = *(const bh8*)(w2base + (size_t)(ni * 8 + ko) * 512);

    float bias2v[4];
    #pragma unroll
    for (int ni = 0; ni < 4; ++ni) bias2v[ni] = mb2[n0 + ni * 16 + lr];

    #pragma unroll
    for (int mi = 0; mi < 4; ++mi)
        #pragma unroll
        for (int ni = 0; ni < 4; ++ni)
            #pragma unroll
            for (int rr = 0; rr < 4; ++rr) {
                float vv = acc[mi][ni][rr] + bias1v[ni];
                float t = 0.7978845608028654f * (vv + 0.044715f * vv * vv * vv);
                float ge = vv / (1.0f + __expf(-2.0f * t));
                As[mi * 16 + lk * 4 + rr][n0 + ni * 16 + lr] = f2bf(ge);
            }
    __syncthreads();

    fx4 acc2[4][4];
    #pragma unroll
    for (int mi = 0; mi < 4; ++mi)
        #pragma unroll
        for (int ni = 0; ni < 4; ++ni) acc2[mi][ni] = zero;

    #pragma unroll
    for (int ko = 0; ko < 8; ++ko) {
        #pragma unroll
        for (int mi = 0; mi < 4; ++mi) {
            bh8 a = *(const bh8*)&As[mi * 16 + lr][ko * 32 + lk * 8];
            #pragma unroll
            for (int ni = 0; ni < 4; ++ni)
                acc2[mi][ni] = __builtin_amdgcn_mfma_f32_16x16x32_bf16(a, wf[ni][ko], acc2[mi][ni], 0, 0, 0);
        }
    }

    #pragma unroll
    for (int mi = 0; mi < 4; ++mi)
        #pragma unroll
        for (int ni = 0; ni < 4; ++ni)
            #pragma unroll
            for (int rr = 0; rr < 4; ++rr) {
                long row = m0 + mi * 16 + lk * 4 + rr;
                int col = n0 + ni * 16 + lr;
                long idx = row * DIM + col;
                xio[idx] = xio[idx] + acc2[mi][ni][rr] + bias2v[ni];
            }
}

extern "C" void kernel_launch(void* const* d_in, const int* in_sizes, int n_in,
                              void* d_out, int out_size, void* d_ws, size_t ws_size,
                              hipStream_t stream) {
    const float* x    = (const float*)d_in[0];
    const float* g1   = (const float*)d_in[1];
    const float* b1   = (const float*)d_in[2];
    const float* btab = (const float*)d_in[3];
    const float* g2   = (const float*)d_in[6];
    const float* b2   = (const float*)d_in[7];
    const float* w1   = (const float*)d_in[8];
    const float* mb1  = (const float*)d_in[9];
    const float* w2   = (const float*)d_in[10];
    const float* mb2  = (const float*)d_in[11];
    float* out = (float*)d_out;
    unsigned short* wtf = (unsigned short*)d_ws;
    unsigned short* x1h = wtf + 131072;   // after 256 KB weight area

    size_t need = 131072ull * 2 + (size_t)NTOKEN * DIM * 2;   // 256 KB + 84 MB

    prep_kernel<<<64, 256, 0, stream>>>(w1, w2, wtf);
    if (ws_size >= need) {
        attn_kernel<1><<<16384, 256, 0, stream>>>(x, g1, b1, btab, nullptr, x1h);
        mlp_bf_kernel<<<2560, 256, 0, stream>>>(x1h, out, g2, b2, wtf, mb1, mb2);
    } else {
        attn_kernel<0><<<16384, 256, 0, stream>>>(x, g1, b1, btab, out, nullptr);
        mlp_kernel<<<2560, 256, 0, stream>>>(out, g2, b2, wtf, mb1, mb2);
    }
}

// Round 6
// 289.908 us; speedup vs baseline: 1.1407x; 1.1407x over previous
//
#include <hip/hip_runtime.h>
#include <hip/hip_bf16.h>
#include <math.h>

#define DIM 256
#define NHEAD 8
#define HD 32
#define WH 5
#define WW 2
#define NTOK 10
#define WPAT 64
#define LTOK 5120
#define NTOKEN 163840
#define EPS 1e-5f

typedef __attribute__((ext_vector_type(8))) short bh8;
typedef __attribute__((ext_vector_type(4))) short sh4;
typedef __attribute__((ext_vector_type(4))) float fx4;

__device__ inline unsigned short f2bf(float f) {
    unsigned int u = __builtin_bit_cast(unsigned int, f);
    u += 0x7fffu + ((u >> 16) & 1u);
    return (unsigned short)(u >> 16);
}
__device__ inline float bf2f(unsigned short h) {
    return __builtin_bit_cast(float, (unsigned int)h << 16);
}

__device__ inline float wave_reduce_sum(float v) {
    #pragma unroll
    for (int off = 32; off > 0; off >>= 1) v += __shfl_xor(v, off);
    return v;
}

// ---- kernel 0: weight prep. f32 [K][N] -> bf16 MFMA-fragment order:
//      wtf[((mat*4+s)*4+ni)*8+ko][lane][j] = W[ko*32+(lane>>4)*8+j][s*64+ni*16+(lane&15)]
__global__ void prep_kernel(const float* __restrict__ w1,
                            const float* __restrict__ w2,
                            unsigned short* __restrict__ wtf) {
    int gid = blockIdx.x * 256 + threadIdx.x;   // 16384 threads, 8 shorts each
    int lane = gid & 63;
    int ko = (gid >> 6) & 7;
    int ni = (gid >> 9) & 3;
    int s  = (gid >> 11) & 3;
    int mat = gid >> 13;
    const float* src = mat ? w2 : w1;
    int col = s * 64 + ni * 16 + (lane & 15);
    int k0 = ko * 32 + (lane >> 4) * 8;
    unsigned short* dst = wtf + (size_t)gid * 8;
    #pragma unroll
    for (int j = 0; j < 8; ++j)
        dst[j] = f2bf(src[(k0 + j) * 256 + col]);
}

// ---------------- kernel 1: LN1 + window attention + residual -> x1 -----------------
// BF=1: write bf16 to x1h (workspace). BF=0: write f32 to x1f (d_out).
template<int BF>
__global__ __launch_bounds__(256) void attn_kernel(
    const float* __restrict__ x, const float* __restrict__ g1,
    const float* __restrict__ b1, const float* __restrict__ btab,
    float* __restrict__ x1f, unsigned short* __restrict__ x1h) {
    __shared__ float xs[NTOK][DIM + 8];
    __shared__ float hs[NTOK][DIM + 8];
    __shared__ float pm[NHEAD * NTOK * NTOK];

    int w = blockIdx.x;              // 0..16383
    int b = w >> 9;
    int rh = (w >> 5) & 15;
    int cw = w & 31;
    int tid = threadIdx.x;
    int lane = tid & 63;
    int wave = tid >> 6;
    long base = (long)b * LTOK + rh * (WH * WPAT) + cw * WW;

    #pragma unroll
    for (int i = 0; i < WH; ++i) {
        const float2* src = (const float2*)(x + (base + (long)i * WPAT) * DIM);
        float2 v = src[tid];
        int p = tid * 2;
        int tok = i * 2 + (p >> 8);
        int c = p & 255;
        *(float2*)&xs[tok][c] = v;
    }
    __syncthreads();

    float4 g4 = *(const float4*)(g1 + lane * 4);
    float4 b4 = *(const float4*)(b1 + lane * 4);
    for (int tok = wave; tok < NTOK; tok += 4) {
        float4 v = *(const float4*)&xs[tok][lane * 4];
        float s = v.x + v.y + v.z + v.w;
        float q = v.x * v.x + v.y * v.y + v.z * v.z + v.w * v.w;
        s = wave_reduce_sum(s);
        q = wave_reduce_sum(q);
        float mean = s * (1.0f / DIM);
        float var = q * (1.0f / DIM) - mean * mean;
        float rstd = rsqrtf(var + EPS);
        float4 h;
        h.x = (v.x - mean) * rstd * g4.x + b4.x;
        h.y = (v.y - mean) * rstd * g4.y + b4.y;
        h.z = (v.z - mean) * rstd * g4.z + b4.z;
        h.w = (v.w - mean) * rstd * g4.w + b4.w;
        *(float4*)&hs[tok][lane * 4] = h;
    }
    __syncthreads();

    const float scale = 0.17677669529663689f;   // 32^-0.5
    for (int item = tid; item < NHEAD * NTOK * NTOK; item += 256) {
        int head = item / 100;
        int rem = item - head * 100;
        int q = rem / 10;
        int k = rem - q * 10;
        float acc = 0.f;
        #pragma unroll
        for (int d = 0; d < HD; ++d)
            acc += hs[q][head * HD + d] * hs[k][head * HD + d];
        int iq = q >> 1, jq = q & 1, ik = k >> 1, jk = k & 1;
        int bidx = (iq - ik + WH - 1) * (2 * WW - 1) + (jq - jk + WW - 1);
        pm[item] = acc * scale + btab[bidx * NHEAD + head];
    }
    __syncthreads();

    if (tid < NHEAD * NTOK) {
        float* row = pm + tid * NTOK;
        float m = row[0];
        #pragma unroll
        for (int k = 1; k < NTOK; ++k) m = fmaxf(m, row[k]);
        float e[NTOK];
        float s = 0.f;
        #pragma unroll
        for (int k = 0; k < NTOK; ++k) { e[k] = __expf(row[k] - m); s += e[k]; }
        float inv = 1.0f / s;
        #pragma unroll
        for (int k = 0; k < NTOK; ++k) row[k] = e[k] * inv;
    }
    __syncthreads();

    int head = tid >> 5;
    float hv[NTOK];
    #pragma unroll
    for (int k = 0; k < NTOK; ++k) hv[k] = hs[k][tid];
    #pragma unroll
    for (int q = 0; q < NTOK; ++q) {
        const float* pr = pm + (head * NTOK + q) * NTOK;
        float acc = 0.f;
        #pragma unroll
        for (int k = 0; k < NTOK; ++k) acc += pr[k] * hv[k];
        float o = xs[q][tid] + acc;
        long l = base + (q >> 1) * WPAT + (q & 1);
        if (BF) x1h[l * DIM + tid] = f2bf(o);
        else    x1f[l * DIM + tid] = o;
    }
}

// ---------------- kernel 2 (main): bf16 x1 in ws -> LN2 + MLP -> f32 d_out ----------
// Round-3 register discipline: no min-waves bound (compiler landed at 108 VGPR with
// this exact phase structure), all bulk state phase-scoped, epilogue re-reads x1.
__global__ __launch_bounds__(256) void mlp_bf_kernel(
    const unsigned short* __restrict__ x1h, float* __restrict__ out,
    const float* __restrict__ g2, const float* __restrict__ b2,
    const unsigned short* __restrict__ wtf,
    const float* __restrict__ mb1, const float* __restrict__ mb2) {
    __shared__ unsigned short As[64][DIM + 8];

    int m0 = blockIdx.x * 64;
    int tid = threadIdx.x;
    int lane = tid & 63;
    int wave = tid >> 6;
    int lr = lane & 15;
    int lk = lane >> 4;
    int n0 = wave * 64;

    const unsigned short* w1base = wtf + (size_t)wave * 16384 + (size_t)lane * 8;
    const unsigned short* w2base = wtf + 65536 + (size_t)wave * 16384 + (size_t)lane * 8;

    int r = tid >> 2;          // row 0..63
    int q = tid & 3;           // 64-ch segment 0..3
    const bh8* rowp = (const bh8*)(x1h + (size_t)(m0 + r) * DIM + q * 64);

    // GEMM1 weight burst (issued first; latency overlaps LN2 phase)
    bh8 wf[4][8];
    #pragma unroll
    for (int ni = 0; ni < 4; ++ni)
        #pragma unroll
        for (int ko = 0; ko < 8; ++ko)
            wf[ni][ko] = *(const bh8*)(w1base + (size_t)(ni * 8 + ko) * 512);

    float bias1v[4];
    #pragma unroll
    for (int ni = 0; ni < 4; ++ni) bias1v[ni] = mb1[n0 + ni * 16 + lr];

    // ---- LN2: load bf16 segment (dies after this phase)
    {
        bh8 xv[8];
        #pragma unroll
        for (int j = 0; j < 8; ++j) xv[j] = rowp[j];

        float s = 0.f, sq = 0.f;
        #pragma unroll
        for (int j = 0; j < 8; ++j)
            #pragma unroll
            for (int e = 0; e < 8; ++e) {
                float f = bf2f((unsigned short)xv[j][e]);
                s += f; sq += f * f;
            }
        s += __shfl_xor(s, 1);  s += __shfl_xor(s, 2);
        sq += __shfl_xor(sq, 1); sq += __shfl_xor(sq, 2);
        float mean = s * (1.0f / DIM);
        float var = sq * (1.0f / DIM) - mean * mean;
        float rstd = rsqrtf(var + EPS);

        const float4* g4p = (const float4*)g2;
        const float4* b4p = (const float4*)b2;
        #pragma unroll
        for (int j = 0; j < 8; ++j) {
            int c4 = q * 16 + j * 2;
            float4 gA = g4p[c4],     bA = b4p[c4];
            float4 gB = g4p[c4 + 1], bB = b4p[c4 + 1];
            bh8 h;
            h[0] = (short)f2bf((bf2f((unsigned short)xv[j][0]) - mean) * rstd * gA.x + bA.x);
            h[1] = (short)f2bf((bf2f((unsigned short)xv[j][1]) - mean) * rstd * gA.y + bA.y);
            h[2] = (short)f2bf((bf2f((unsigned short)xv[j][2]) - mean) * rstd * gA.z + bA.z);
            h[3] = (short)f2bf((bf2f((unsigned short)xv[j][3]) - mean) * rstd * gA.w + bA.w);
            h[4] = (short)f2bf((bf2f((unsigned short)xv[j][4]) - mean) * rstd * gB.x + bB.x);
            h[5] = (short)f2bf((bf2f((unsigned short)xv[j][5]) - mean) * rstd * gB.y + bB.y);
            h[6] = (short)f2bf((bf2f((unsigned short)xv[j][6]) - mean) * rstd * gB.z + bB.z);
            h[7] = (short)f2bf((bf2f((unsigned short)xv[j][7]) - mean) * rstd * gB.w + bB.w);
            *(bh8*)&As[r][q * 64 + j * 8] = h;
        }
    }
    __syncthreads();

    const fx4 zero = {0.f, 0.f, 0.f, 0.f};

    // ---- GEMM1 (round-3 inner loop: a[4] per ko)
    fx4 acc[4][4];
    #pragma unroll
    for (int mi = 0; mi < 4; ++mi)
        #pragma unroll
        for (int ni = 0; ni < 4; ++ni) acc[mi][ni] = zero;

    #pragma unroll
    for (int ko = 0; ko < 8; ++ko) {
        bh8 a[4];
        #pragma unroll
        for (int mi = 0; mi < 4; ++mi)
            a[mi] = *(const bh8*)&As[mi * 16 + lr][ko * 32 + lk * 8];
        #pragma unroll
        for (int mi = 0; mi < 4; ++mi)
            #pragma unroll
            for (int ni = 0; ni < 4; ++ni)
                acc[mi][ni] = __builtin_amdgcn_mfma_f32_16x16x32_bf16(a[mi], wf[ni][ko], acc[mi][ni], 0, 0, 0);
    }
    __syncthreads();

    // GEMM2 weight burst; hides under gelu VALU
    #pragma unroll
    for (int ni = 0; ni < 4; ++ni)
        #pragma unroll
        for (int ko = 0; ko < 8; ++ko)
            wf[ni][ko] = *(const bh8*)(w2base + (size_t)(ni * 8 + ko) * 512);

    float bias2v[4];
    #pragma unroll
    for (int ni = 0; ni < 4; ++ni) bias2v[ni] = mb2[n0 + ni * 16 + lr];

    // ---- bias1 + gelu -> bf16 back into As
    #pragma unroll
    for (int mi = 0; mi < 4; ++mi)
        #pragma unroll
        for (int ni = 0; ni < 4; ++ni)
            #pragma unroll
            for (int rr = 0; rr < 4; ++rr) {
                float vv = acc[mi][ni][rr] + bias1v[ni];
                float t = 0.7978845608028654f * (vv + 0.044715f * vv * vv * vv);
                float ge = vv / (1.0f + __expf(-2.0f * t));
                As[mi * 16 + lk * 4 + rr][n0 + ni * 16 + lr] = f2bf(ge);
            }
    __syncthreads();

    // ---- GEMM2
    fx4 acc2[4][4];
    #pragma unroll
    for (int mi = 0; mi < 4; ++mi)
        #pragma unroll
        for (int ni = 0; ni < 4; ++ni) acc2[mi][ni] = zero;

    #pragma unroll
    for (int ko = 0; ko < 8; ++ko) {
        bh8 a[4];
        #pragma unroll
        for (int mi = 0; mi < 4; ++mi)
            a[mi] = *(const bh8*)&As[mi * 16 + lr][ko * 32 + lk * 8];
        #pragma unroll
        for (int mi = 0; mi < 4; ++mi)
            #pragma unroll
            for (int ni = 0; ni < 4; ++ni)
                acc2[mi][ni] = __builtin_amdgcn_mfma_f32_16x16x32_bf16(a[mi], wf[ni][ko], acc2[mi][ni], 0, 0, 0);
    }
    __syncthreads();

    // ---- stash bias2-added mlp output (bf16) in As for the coalesced epilogue
    #pragma unroll
    for (int mi = 0; mi < 4; ++mi)
        #pragma unroll
        for (int ni = 0; ni < 4; ++ni)
            #pragma unroll
            for (int rr = 0; rr < 4; ++rr)
                As[mi * 16 + lk * 4 + rr][n0 + ni * 16 + lr] = f2bf(acc2[mi][ni][rr] + bias2v[ni]);
    __syncthreads();

    // ---- epilogue: re-read x1 segment (L2-hot) + mlp_out from LDS, float4 stores
    {
        bh8 xv[8];
        #pragma unroll
        for (int j = 0; j < 8; ++j) xv[j] = rowp[j];

        float* orow = out + (size_t)(m0 + r) * DIM + q * 64;
        #pragma unroll
        for (int j = 0; j < 8; ++j) {
            bh8 mv = *(const bh8*)&As[r][q * 64 + j * 8];
            float4 o0, o1;
            o0.x = bf2f((unsigned short)xv[j][0]) + bf2f((unsigned short)mv[0]);
            o0.y = bf2f((unsigned short)xv[j][1]) + bf2f((unsigned short)mv[1]);
            o0.z = bf2f((unsigned short)xv[j][2]) + bf2f((unsigned short)mv[2]);
            o0.w = bf2f((unsigned short)xv[j][3]) + bf2f((unsigned short)mv[3]);
            o1.x = bf2f((unsigned short)xv[j][4]) + bf2f((unsigned short)mv[4]);
            o1.y = bf2f((unsigned short)xv[j][5]) + bf2f((unsigned short)mv[5]);
            o1.z = bf2f((unsigned short)xv[j][6]) + bf2f((unsigned short)mv[6]);
            o1.w = bf2f((unsigned short)xv[j][7]) + bf2f((unsigned short)mv[7]);
            *(float4*)(orow + j * 8)     = o0;
            *(float4*)(orow + j * 8 + 4) = o1;
        }
    }
}

// ---------------- kernel 2 (fallback): round-3 in-place f32 path --------------------
__global__ __launch_bounds__(256, 2) void mlp_kernel(
    float* __restrict__ xio,
    const float* __restrict__ g2, const float* __restrict__ b2,
    const unsigned short* __restrict__ wtf,
    const float* __restrict__ mb1, const float* __restrict__ mb2) {
    __shared__ unsigned short As[64][DIM + 8];

    int m0 = blockIdx.x * 64;
    int tid = threadIdx.x;
    int lane = tid & 63;
    int wave = tid >> 6;
    int lr = lane & 15;
    int lk = lane >> 4;
    int n0 = wave * 64;

    const unsigned short* w1base = wtf + (size_t)wave * 16384 + (size_t)lane * 8;
    const unsigned short* w2base = wtf + 65536 + (size_t)wave * 16384 + (size_t)lane * 8;

    int r = tid >> 2;
    int q = tid & 3;
    const float4* rowp = (const float4*)(xio + (long)(m0 + r) * DIM);
    float4 v[16];
    #pragma unroll
    for (int i = 0; i < 16; ++i) v[i] = rowp[q + 4 * i];

    bh8 wf[4][8];
    #pragma unroll
    for (int ni = 0; ni < 4; ++ni)
        #pragma unroll
        for (int ko = 0; ko < 8; ++ko)
            wf[ni][ko] = *(const bh8*)(w1base + (size_t)(ni * 8 + ko) * 512);

    float bias1v[4];
    #pragma unroll
    for (int ni = 0; ni < 4; ++ni) bias1v[ni] = mb1[n0 + ni * 16 + lr];

    {
        float s = 0.f, sq = 0.f;
        #pragma unroll
        for (int i = 0; i < 16; ++i) {
            s += v[i].x + v[i].y + v[i].z + v[i].w;
            sq += v[i].x * v[i].x + v[i].y * v[i].y + v[i].z * v[i].z + v[i].w * v[i].w;
        }
        s += __shfl_xor(s, 1);  s += __shfl_xor(s, 2);
        sq += __shfl_xor(sq, 1); sq += __shfl_xor(sq, 2);
        float mean = s * (1.0f / DIM);
        float var = sq * (1.0f / DIM) - mean * mean;
        float rstd = rsqrtf(var + EPS);

        const float4* g4p = (const float4*)g2;
        const float4* b4p = (const float4*)b2;
        #pragma unroll
        for (int i = 0; i < 16; ++i) {
            int c4 = q + 4 * i;
            float4 gg = g4p[c4];
            float4 bb = b4p[c4];
            sh4 h;
            h.x = (short)f2bf((v[i].x - mean) * rstd * gg.x + bb.x);
            h.y = (short)f2bf((v[i].y - mean) * rstd * gg.y + bb.y);
            h.z = (short)f2bf((v[i].z - mean) * rstd * gg.z + bb.z);
            h.w = (short)f2bf((v[i].w - mean) * rstd * gg.w + bb.w);
            *(sh4*)&As[r][c4 * 4] = h;
        }
    }
    __syncthreads();

    const fx4 zero = {0.f, 0.f, 0.f, 0.f};

    fx4 acc[4][4];
    #pragma unroll
    for (int mi = 0; mi < 4; ++mi)
        #pragma unroll
        for (int ni = 0; ni < 4; ++ni) acc[mi][ni] = zero;

    #pragma unroll
    for (int ko = 0; ko < 8; ++ko) {
        bh8 a[4];
        #pragma unroll
        for (int mi = 0; mi < 4; ++mi)
            a[mi] = *(const bh8*)&As[mi * 16 + lr][ko * 32 + lk * 8];
        #pragma unroll
        for (int mi = 0; mi < 4; ++mi)
            #pragma unroll
            for (int ni = 0; ni < 4; ++ni)
                acc[mi][ni] = __builtin_amdgcn_mfma_f32_16x16x32_bf16(a[mi], wf[ni][ko], acc[mi][ni], 0, 0, 0);
    }
    __syncthreads();

    #pragma unroll
    for (int ni = 0; ni < 4; ++ni)
        #pragma unroll
        for (int ko = 0; ko < 8; ++ko)
            wf[ni][ko] = *(const bh8*)(w2base + (size_t)(ni * 8 + ko) * 512);

    float bias2v[4];
    #pragma unroll
    for (int ni = 0; ni < 4; ++ni) bias2v[ni] = mb2[n0 + ni * 16 + lr];

    #pragma unroll
    for (int mi = 0; mi < 4; ++mi)
        #pragma unroll
        for (int ni = 0; ni < 4; ++ni)
            #pragma unroll
            for (int rr = 0; rr < 4; ++rr) {
                float vv = acc[mi][ni][rr] + bias1v[ni];
                float t = 0.7978845608028654f * (vv + 0.044715f * vv * vv * vv);
                float ge = vv / (1.0f + __expf(-2.0f * t));
                As[mi * 16 + lk * 4 + rr][n0 + ni * 16 + lr] = f2bf(ge);
            }
    __syncthreads();

    fx4 acc2[4][4];
    #pragma unroll
    for (int mi = 0; mi < 4; ++mi)
        #pragma unroll
        for (int ni = 0; ni < 4; ++ni) acc2[mi][ni] = zero;

    #pragma unroll
    for (int ko = 0; ko < 8; ++ko) {
        bh8 a[4];
        #pragma unroll
        for (int mi = 0; mi < 4; ++mi)
            a[mi] = *(const bh8*)&As[mi * 16 + lr][ko * 32 + lk * 8];
        #pragma unroll
        for (int mi = 0; mi < 4; ++mi)
            #pragma unroll
            for (int ni = 0; ni < 4; ++ni)
                acc2[mi][ni] = __builtin_amdgcn_mfma_f32_16x16x32_bf16(a[mi], wf[ni][ko], acc2[mi][ni], 0, 0, 0);
    }

    #pragma unroll
    for (int mi = 0; mi < 4; ++mi)
        #pragma unroll
        for (int ni = 0; ni < 4; ++ni)
            #pragma unroll
            for (int rr = 0; rr < 4; ++rr) {
                long row = m0 + mi * 16 + lk * 4 + rr;
                int col = n0 + ni * 16 + lr;
                long idx = row * DIM + col;
                xio[idx] = xio[idx] + acc2[mi][ni][rr] + bias2v[ni];
            }
}

extern "C" void kernel_launch(void* const* d_in, const int* in_sizes, int n_in,
                              void* d_out, int out_size, void* d_ws, size_t ws_size,
                              hipStream_t stream) {
    const float* x    = (const float*)d_in[0];
    const float* g1   = (const float*)d_in[1];
    const float* b1   = (const float*)d_in[2];
    const float* btab = (const float*)d_in[3];
    const float* g2   = (const float*)d_in[6];
    const float* b2   = (const float*)d_in[7];
    const float* w1   = (const float*)d_in[8];
    const float* mb1  = (const float*)d_in[9];
    const float* w2   = (const float*)d_in[10];
    const float* mb2  = (const float*)d_in[11];
    float* out = (float*)d_out;
    unsigned short* wtf = (unsigned short*)d_ws;
    unsigned short* x1h = wtf + 131072;   // after 256 KB weight area

    size_t need = 131072ull * 2 + (size_t)NTOKEN * DIM * 2;   // 256 KB + 84 MB

    prep_kernel<<<64, 256, 0, stream>>>(w1, w2, wtf);
    if (ws_size >= need) {
        attn_kernel<1><<<16384, 256, 0, stream>>>(x, g1, b1, btab, nullptr, x1h);
        mlp_bf_kernel<<<2560, 256, 0, stream>>>(x1h, out, g2, b2, wtf, mb1, mb2);
    } else {
        attn_kernel<0><<<16384, 256, 0, stream>>>(x, g1, b1, btab, out, nullptr);
        mlp_kernel<<<2560, 256, 0, stream>>>(out, g2, b2, wtf, mb1, mb2);
    }
}

// Round 7
// 225.909 us; speedup vs baseline: 1.4638x; 1.2833x over previous
//
#include <hip/hip_runtime.h>
#include <hip/hip_bf16.h>
#include <math.h>

#define DIM 256
#define NHEAD 8
#define HD 32
#define WH 5
#define WW 2
#define NTOK 10
#define WPAT 64
#define LTOK 5120
#define NTOKEN 163840
#define EPS 1e-5f

typedef __attribute__((ext_vector_type(8))) short bh8;
typedef __attribute__((ext_vector_type(4))) short sh4;
typedef __attribute__((ext_vector_type(4))) float fx4;

__device__ inline unsigned short f2bf(float f) {
    unsigned int u = __builtin_bit_cast(unsigned int, f);
    u += 0x7fffu + ((u >> 16) & 1u);
    return (unsigned short)(u >> 16);
}
__device__ inline float bf2f(unsigned short h) {
    return __builtin_bit_cast(float, (unsigned int)h << 16);
}

__device__ inline float wave_reduce_sum(float v) {
    #pragma unroll
    for (int off = 32; off > 0; off >>= 1) v += __shfl_xor(v, off);
    return v;
}

// ---- kernel 0: weight prep. f32 [K][N] -> bf16 MFMA-fragment order:
//      wtf[((mat*4+s)*4+ni)*8+ko][lane][j] = W[ko*32+(lane>>4)*8+j][s*64+ni*16+(lane&15)]
__global__ void prep_kernel(const float* __restrict__ w1,
                            const float* __restrict__ w2,
                            unsigned short* __restrict__ wtf) {
    int gid = blockIdx.x * 256 + threadIdx.x;   // 16384 threads, 8 shorts each
    int lane = gid & 63;
    int ko = (gid >> 6) & 7;
    int ni = (gid >> 9) & 3;
    int s  = (gid >> 11) & 3;
    int mat = gid >> 13;
    const float* src = mat ? w2 : w1;
    int col = s * 64 + ni * 16 + (lane & 15);
    int k0 = ko * 32 + (lane >> 4) * 8;
    unsigned short* dst = wtf + (size_t)gid * 8;
    #pragma unroll
    for (int j = 0; j < 8; ++j)
        dst[j] = f2bf(src[(k0 + j) * 256 + col]);
}

// ---------------- kernel 1: LN1 + window attention + residual -> x1 -----------------
// BF=1: write bf16 to x1h (workspace). BF=0: write f32 to x1f (d_out).
template<int BF>
__global__ __launch_bounds__(256) void attn_kernel(
    const float* __restrict__ x, const float* __restrict__ g1,
    const float* __restrict__ b1, const float* __restrict__ btab,
    float* __restrict__ x1f, unsigned short* __restrict__ x1h) {
    __shared__ float xs[NTOK][DIM + 8];
    __shared__ float hs[NTOK][DIM + 8];
    __shared__ float pm[NHEAD * NTOK * NTOK];

    int w = blockIdx.x;              // 0..16383
    int b = w >> 9;
    int rh = (w >> 5) & 15;
    int cw = w & 31;
    int tid = threadIdx.x;
    int lane = tid & 63;
    int wave = tid >> 6;
    long base = (long)b * LTOK + rh * (WH * WPAT) + cw * WW;

    #pragma unroll
    for (int i = 0; i < WH; ++i) {
        const float2* src = (const float2*)(x + (base + (long)i * WPAT) * DIM);
        float2 v = src[tid];
        int p = tid * 2;
        int tok = i * 2 + (p >> 8);
        int c = p & 255;
        *(float2*)&xs[tok][c] = v;
    }
    __syncthreads();

    float4 g4 = *(const float4*)(g1 + lane * 4);
    float4 b4 = *(const float4*)(b1 + lane * 4);
    for (int tok = wave; tok < NTOK; tok += 4) {
        float4 v = *(const float4*)&xs[tok][lane * 4];
        float s = v.x + v.y + v.z + v.w;
        float q = v.x * v.x + v.y * v.y + v.z * v.z + v.w * v.w;
        s = wave_reduce_sum(s);
        q = wave_reduce_sum(q);
        float mean = s * (1.0f / DIM);
        float var = q * (1.0f / DIM) - mean * mean;
        float rstd = rsqrtf(var + EPS);
        float4 h;
        h.x = (v.x - mean) * rstd * g4.x + b4.x;
        h.y = (v.y - mean) * rstd * g4.y + b4.y;
        h.z = (v.z - mean) * rstd * g4.z + b4.z;
        h.w = (v.w - mean) * rstd * g4.w + b4.w;
        *(float4*)&hs[tok][lane * 4] = h;
    }
    __syncthreads();

    const float scale = 0.17677669529663689f;   // 32^-0.5
    for (int item = tid; item < NHEAD * NTOK * NTOK; item += 256) {
        int head = item / 100;
        int rem = item - head * 100;
        int q = rem / 10;
        int k = rem - q * 10;
        float acc = 0.f;
        #pragma unroll
        for (int d = 0; d < HD; ++d)
            acc += hs[q][head * HD + d] * hs[k][head * HD + d];
        int iq = q >> 1, jq = q & 1, ik = k >> 1, jk = k & 1;
        int bidx = (iq - ik + WH - 1) * (2 * WW - 1) + (jq - jk + WW - 1);
        pm[item] = acc * scale + btab[bidx * NHEAD + head];
    }
    __syncthreads();

    if (tid < NHEAD * NTOK) {
        float* row = pm + tid * NTOK;
        float m = row[0];
        #pragma unroll
        for (int k = 1; k < NTOK; ++k) m = fmaxf(m, row[k]);
        float e[NTOK];
        float s = 0.f;
        #pragma unroll
        for (int k = 0; k < NTOK; ++k) { e[k] = __expf(row[k] - m); s += e[k]; }
        float inv = 1.0f / s;
        #pragma unroll
        for (int k = 0; k < NTOK; ++k) row[k] = e[k] * inv;
    }
    __syncthreads();

    int head = tid >> 5;
    float hv[NTOK];
    #pragma unroll
    for (int k = 0; k < NTOK; ++k) hv[k] = hs[k][tid];
    #pragma unroll
    for (int q = 0; q < NTOK; ++q) {
        const float* pr = pm + (head * NTOK + q) * NTOK;
        float acc = 0.f;
        #pragma unroll
        for (int k = 0; k < NTOK; ++k) acc += pr[k] * hv[k];
        float o = xs[q][tid] + acc;
        long l = base + (q >> 1) * WPAT + (q & 1);
        if (BF) x1h[l * DIM + tid] = f2bf(o);
        else    x1f[l * DIM + tid] = o;
    }
}

// ---------------- kernel 2 (main): bf16 x1 -> LN2 + MLP -> f32 d_out ---------------
// 512 threads / 8 waves; each wave owns a 32-col N-strip: wf[2][8] + acc[4][2]
// halves per-wave register state vs the 4-wave version (which spilled at 136 VGPR).
__global__ __launch_bounds__(512) void mlp_bf_kernel(
    const unsigned short* __restrict__ x1h, float* __restrict__ out,
    const float* __restrict__ g2, const float* __restrict__ b2,
    const unsigned short* __restrict__ wtf,
    const float* __restrict__ mb1, const float* __restrict__ mb2) {
    __shared__ unsigned short As[64][DIM + 8];

    int m0 = blockIdx.x * 64;
    int tid = threadIdx.x;       // 0..511
    int lane = tid & 63;
    int wave = tid >> 6;         // 0..7
    int lr = lane & 15;
    int lk = lane >> 4;
    int n0 = wave * 32;
    int s  = wave >> 1;          // 64-col strip index in prep layout
    int nb = (wave & 1) * 2;     // ni base within strip

    const unsigned short* w1base = wtf + (size_t)(s * 4 + nb) * 8 * 512 + (size_t)lane * 8;
    const unsigned short* w2base = w1base + 65536;

    int r = tid >> 3;            // row 0..63
    int q = tid & 7;             // 32-chan segment 0..7
    const bh8* rowp = (const bh8*)(x1h + (size_t)(m0 + r) * DIM + q * 32);

    // GEMM1 weight burst (16 coalesced dwordx4/lane); latency overlaps LN2
    bh8 wf[2][8];
    #pragma unroll
    for (int ni = 0; ni < 2; ++ni)
        #pragma unroll
        for (int ko = 0; ko < 8; ++ko)
            wf[ni][ko] = *(const bh8*)(w1base + (size_t)(ni * 8 + ko) * 512);

    float bias1v[2];
    #pragma unroll
    for (int ni = 0; ni < 2; ++ni) bias1v[ni] = mb1[n0 + ni * 16 + lr];

    // ---- LN2: 8 threads/row, 32 chans each
    {
        bh8 xv[4];
        #pragma unroll
        for (int j = 0; j < 4; ++j) xv[j] = rowp[j];

        float sm = 0.f, sq = 0.f;
        #pragma unroll
        for (int j = 0; j < 4; ++j)
            #pragma unroll
            for (int e = 0; e < 8; ++e) {
                float f = bf2f((unsigned short)xv[j][e]);
                sm += f; sq += f * f;
            }
        sm += __shfl_xor(sm, 1); sm += __shfl_xor(sm, 2); sm += __shfl_xor(sm, 4);
        sq += __shfl_xor(sq, 1); sq += __shfl_xor(sq, 2); sq += __shfl_xor(sq, 4);
        float mean = sm * (1.0f / DIM);
        float var = sq * (1.0f / DIM) - mean * mean;
        float rstd = rsqrtf(var + EPS);

        const float4* g4p = (const float4*)g2;
        const float4* b4p = (const float4*)b2;
        #pragma unroll
        for (int j = 0; j < 4; ++j) {
            int c4 = q * 8 + j * 2;
            float4 gA = g4p[c4],     bA = b4p[c4];
            float4 gB = g4p[c4 + 1], bB = b4p[c4 + 1];
            bh8 h;
            h[0] = (short)f2bf((bf2f((unsigned short)xv[j][0]) - mean) * rstd * gA.x + bA.x);
            h[1] = (short)f2bf((bf2f((unsigned short)xv[j][1]) - mean) * rstd * gA.y + bA.y);
            h[2] = (short)f2bf((bf2f((unsigned short)xv[j][2]) - mean) * rstd * gA.z + bA.z);
            h[3] = (short)f2bf((bf2f((unsigned short)xv[j][3]) - mean) * rstd * gA.w + bA.w);
            h[4] = (short)f2bf((bf2f((unsigned short)xv[j][4]) - mean) * rstd * gB.x + bB.x);
            h[5] = (short)f2bf((bf2f((unsigned short)xv[j][5]) - mean) * rstd * gB.y + bB.y);
            h[6] = (short)f2bf((bf2f((unsigned short)xv[j][6]) - mean) * rstd * gB.z + bB.z);
            h[7] = (short)f2bf((bf2f((unsigned short)xv[j][7]) - mean) * rstd * gB.w + bB.w);
            *(bh8*)&As[r][q * 32 + j * 8] = h;
        }
    }
    __syncthreads();

    const fx4 zero = {0.f, 0.f, 0.f, 0.f};

    // ---- GEMM1: 64 MFMA/wave, full As read, 32-col N strip
    fx4 acc[4][2];
    #pragma unroll
    for (int mi = 0; mi < 4; ++mi)
        #pragma unroll
        for (int ni = 0; ni < 2; ++ni) acc[mi][ni] = zero;

    #pragma unroll
    for (int ko = 0; ko < 8; ++ko) {
        bh8 a[4];
        #pragma unroll
        for (int mi = 0; mi < 4; ++mi)
            a[mi] = *(const bh8*)&As[mi * 16 + lr][ko * 32 + lk * 8];
        #pragma unroll
        for (int mi = 0; mi < 4; ++mi)
            #pragma unroll
            for (int ni = 0; ni < 2; ++ni)
                acc[mi][ni] = __builtin_amdgcn_mfma_f32_16x16x32_bf16(a[mi], wf[ni][ko], acc[mi][ni], 0, 0, 0);
    }
    __syncthreads();

    // GEMM2 weight burst; hides under gelu VALU
    #pragma unroll
    for (int ni = 0; ni < 2; ++ni)
        #pragma unroll
        for (int ko = 0; ko < 8; ++ko)
            wf[ni][ko] = *(const bh8*)(w2base + (size_t)(ni * 8 + ko) * 512);

    float bias2v[2];
    #pragma unroll
    for (int ni = 0; ni < 2; ++ni) bias2v[ni] = mb2[n0 + ni * 16 + lr];

    // ---- bias1 + gelu -> bf16 back into As
    #pragma unroll
    for (int mi = 0; mi < 4; ++mi)
        #pragma unroll
        for (int ni = 0; ni < 2; ++ni)
            #pragma unroll
            for (int rr = 0; rr < 4; ++rr) {
                float vv = acc[mi][ni][rr] + bias1v[ni];
                float t = 0.7978845608028654f * (vv + 0.044715f * vv * vv * vv);
                float ge = vv / (1.0f + __expf(-2.0f * t));
                As[mi * 16 + lk * 4 + rr][n0 + ni * 16 + lr] = f2bf(ge);
            }
    __syncthreads();

    // ---- GEMM2
    fx4 acc2[4][2];
    #pragma unroll
    for (int mi = 0; mi < 4; ++mi)
        #pragma unroll
        for (int ni = 0; ni < 2; ++ni) acc2[mi][ni] = zero;

    #pragma unroll
    for (int ko = 0; ko < 8; ++ko) {
        bh8 a[4];
        #pragma unroll
        for (int mi = 0; mi < 4; ++mi)
            a[mi] = *(const bh8*)&As[mi * 16 + lr][ko * 32 + lk * 8];
        #pragma unroll
        for (int mi = 0; mi < 4; ++mi)
            #pragma unroll
            for (int ni = 0; ni < 2; ++ni)
                acc2[mi][ni] = __builtin_amdgcn_mfma_f32_16x16x32_bf16(a[mi], wf[ni][ko], acc2[mi][ni], 0, 0, 0);
    }
    __syncthreads();

    // ---- stash bias2-added mlp output (bf16) in As for the coalesced epilogue
    #pragma unroll
    for (int mi = 0; mi < 4; ++mi)
        #pragma unroll
        for (int ni = 0; ni < 2; ++ni)
            #pragma unroll
            for (int rr = 0; rr < 4; ++rr)
                As[mi * 16 + lk * 4 + rr][n0 + ni * 16 + lr] = f2bf(acc2[mi][ni][rr] + bias2v[ni]);
    __syncthreads();

    // ---- epilogue: re-read x1 segment (L2-hot) + mlp_out from LDS, float4 stores
    {
        bh8 xv[4];
        #pragma unroll
        for (int j = 0; j < 4; ++j) xv[j] = rowp[j];

        float* orow = out + (size_t)(m0 + r) * DIM + q * 32;
        #pragma unroll
        for (int j = 0; j < 4; ++j) {
            bh8 mv = *(const bh8*)&As[r][q * 32 + j * 8];
            float4 o0, o1;
            o0.x = bf2f((unsigned short)xv[j][0]) + bf2f((unsigned short)mv[0]);
            o0.y = bf2f((unsigned short)xv[j][1]) + bf2f((unsigned short)mv[1]);
            o0.z = bf2f((unsigned short)xv[j][2]) + bf2f((unsigned short)mv[2]);
            o0.w = bf2f((unsigned short)xv[j][3]) + bf2f((unsigned short)mv[3]);
            o1.x = bf2f((unsigned short)xv[j][4]) + bf2f((unsigned short)mv[4]);
            o1.y = bf2f((unsigned short)xv[j][5]) + bf2f((unsigned short)mv[5]);
            o1.z = bf2f((unsigned short)xv[j][6]) + bf2f((unsigned short)mv[6]);
            o1.w = bf2f((unsigned short)xv[j][7]) + bf2f((unsigned short)mv[7]);
            *(float4*)(orow + j * 8)     = o0;
            *(float4*)(orow + j * 8 + 4) = o1;
        }
    }
}

// ---------------- kernel 2 (fallback): round-3 in-place f32 path --------------------
__global__ __launch_bounds__(256, 2) void mlp_kernel(
    float* __restrict__ xio,
    const float* __restrict__ g2, const float* __restrict__ b2,
    const unsigned short* __restrict__ wtf,
    const float* __restrict__ mb1, const float* __restrict__ mb2) {
    __shared__ unsigned short As[64][DIM + 8];

    int m0 = blockIdx.x * 64;
    int tid = threadIdx.x;
    int lane = tid & 63;
    int wave = tid >> 6;
    int lr = lane & 15;
    int lk = lane >> 4;
    int n0 = wave * 64;

    const unsigned short* w1base = wtf + (size_t)wave * 16384 + (size_t)lane * 8;
    const unsigned short* w2base = wtf + 65536 + (size_t)wave * 16384 + (size_t)lane * 8;

    int r = tid >> 2;
    int q = tid & 3;
    const float4* rowp = (const float4*)(xio + (long)(m0 + r) * DIM);
    float4 v[16];
    #pragma unroll
    for (int i = 0; i < 16; ++i) v[i] = rowp[q + 4 * i];

    bh8 wf[4][8];
    #pragma unroll
    for (int ni = 0; ni < 4; ++ni)
        #pragma unroll
        for (int ko = 0; ko < 8; ++ko)
            wf[ni][ko] = *(const bh8*)(w1base + (size_t)(ni * 8 + ko) * 512);

    float bias1v[4];
    #pragma unroll
    for (int ni = 0; ni < 4; ++ni) bias1v[ni] = mb1[n0 + ni * 16 + lr];

    {
        float s = 0.f, sq = 0.f;
        #pragma unroll
        for (int i = 0; i < 16; ++i) {
            s += v[i].x + v[i].y + v[i].z + v[i].w;
            sq += v[i].x * v[i].x + v[i].y * v[i].y + v[i].z * v[i].z + v[i].w * v[i].w;
        }
        s += __shfl_xor(s, 1);  s += __shfl_xor(s, 2);
        sq += __shfl_xor(sq, 1); sq += __shfl_xor(sq, 2);
        float mean = s * (1.0f / DIM);
        float var = sq * (1.0f / DIM) - mean * mean;
        float rstd = rsqrtf(var + EPS);

        const float4* g4p = (const float4*)g2;
        const float4* b4p = (const float4*)b2;
        #pragma unroll
        for (int i = 0; i < 16; ++i) {
            int c4 = q + 4 * i;
            float4 gg = g4p[c4];
            float4 bb = b4p[c4];
            sh4 h;
            h.x = (short)f2bf((v[i].x - mean) * rstd * gg.x + bb.x);
            h.y = (short)f2bf((v[i].y - mean) * rstd * gg.y + bb.y);
            h.z = (short)f2bf((v[i].z - mean) * rstd * gg.z + bb.z);
            h.w = (short)f2bf((v[i].w - mean) * rstd * gg.w + bb.w);
            *(sh4*)&As[r][c4 * 4] = h;
        }
    }
    __syncthreads();

    const fx4 zero = {0.f, 0.f, 0.f, 0.f};

    fx4 acc[4][4];
    #pragma unroll
    for (int mi = 0; mi < 4; ++mi)
        #pragma unroll
        for (int ni = 0; ni < 4; ++ni) acc[mi][ni] = zero;

    #pragma unroll
    for (int ko = 0; ko < 8; ++ko) {
        bh8 a[4];
        #pragma unroll
        for (int mi = 0; mi < 4; ++mi)
            a[mi] = *(const bh8*)&As[mi * 16 + lr][ko * 32 + lk * 8];
        #pragma unroll
        for (int mi = 0; mi < 4; ++mi)
            #pragma unroll
            for (int ni = 0; ni < 4; ++ni)
                acc[mi][ni] = __builtin_amdgcn_mfma_f32_16x16x32_bf16(a[mi], wf[ni][ko], acc[mi][ni], 0, 0, 0);
    }
    __syncthreads();

    #pragma unroll
    for (int ni = 0; ni < 4; ++ni)
        #pragma unroll
        for (int ko = 0; ko < 8; ++ko)
            wf[ni][ko] = *(const bh8*)(w2base + (size_t)(ni * 8 + ko) * 512);

    float bias2v[4];
    #pragma unroll
    for (int ni = 0; ni < 4; ++ni) bias2v[ni] = mb2[n0 + ni * 16 + lr];

    #pragma unroll
    for (int mi = 0; mi < 4; ++mi)
        #pragma unroll
        for (int ni = 0; ni < 4; ++ni)
            #pragma unroll
            for (int rr = 0; rr < 4; ++rr) {
                float vv = acc[mi][ni][rr] + bias1v[ni];
                float t = 0.7978845608028654f * (vv + 0.044715f * vv * vv * vv);
                float ge = vv / (1.0f + __expf(-2.0f * t));
                As[mi * 16 + lk * 4 + rr][n0 + ni * 16 + lr] = f2bf(ge);
            }
    __syncthreads();

    fx4 acc2[4][4];
    #pragma unroll
    for (int mi = 0; mi < 4; ++mi)
        #pragma unroll
        for (int ni = 0; ni < 4; ++ni) acc2[mi][ni] = zero;

    #pragma unroll
    for (int ko = 0; ko < 8; ++ko) {
        bh8 a[4];
        #pragma unroll
        for (int mi = 0; mi < 4; ++mi)
            a[mi] = *(const bh8*)&As[mi * 16 + lr][ko * 32 + lk * 8];
        #pragma unroll
        for (int mi = 0; mi < 4; ++mi)
            #pragma unroll
            for (int ni = 0; ni < 4; ++ni)
                acc2[mi][ni] = __builtin_amdgcn_mfma_f32_16x16x32_bf16(a[mi], wf[ni][ko], acc2[mi][ni], 0, 0, 0);
    }

    #pragma unroll
    for (int mi = 0; mi < 4; ++mi)
        #pragma unroll
        for (int ni = 0; ni < 4; ++ni)
            #pragma unroll
            for (int rr = 0; rr < 4; ++rr) {
                long row = m0 + mi * 16 + lk * 4 + rr;
                int col = n0 + ni * 16 + lr;
                long idx = row * DIM + col;
                xio[idx] = xio[idx] + acc2[mi][ni][rr] + bias2v[ni];
            }
}

extern "C" void kernel_launch(void* const* d_in, const int* in_sizes, int n_in,
                              void* d_out, int out_size, void* d_ws, size_t ws_size,
                              hipStream_t stream) {
    const float* x    = (const float*)d_in[0];
    const float* g1   = (const float*)d_in[1];
    const float* b1   = (const float*)d_in[2];
    const float* btab = (const float*)d_in[3];
    const float* g2   = (const float*)d_in[6];
    const float* b2   = (const float*)d_in[7];
    const float* w1   = (const float*)d_in[8];
    const float* mb1  = (const float*)d_in[9];
    const float* w2   = (const float*)d_in[10];
    const float* mb2  = (const float*)d_in[11];
    float* out = (float*)d_out;
    unsigned short* wtf = (unsigned short*)d_ws;
    unsigned short* x1h = wtf + 131072;   // after 256 KB weight area

    size_t need = 131072ull * 2 + (size_t)NTOKEN * DIM * 2;   // 256 KB + 84 MB

    prep_kernel<<<64, 256, 0, stream>>>(w1, w2, wtf);
    if (ws_size >= need) {
        attn_kernel<1><<<16384, 256, 0, stream>>>(x, g1, b1, btab, nullptr, x1h);
        mlp_bf_kernel<<<2560, 512, 0, stream>>>(x1h, out, g2, b2, wtf, mb1, mb2);
    } else {
        attn_kernel<0><<<16384, 256, 0, stream>>>(x, g1, b1, btab, out, nullptr);
        mlp_kernel<<<2560, 256, 0, stream>>>(out, g2, b2, wtf, mb1, mb2);
    }
}

// Round 8
// 222.277 us; speedup vs baseline: 1.4877x; 1.0163x over previous
//
#include <hip/hip_runtime.h>
#include <hip/hip_bf16.h>
#include <math.h>

#define DIM 256
#define NHEAD 8
#define HD 32
#define WH 5
#define WW 2
#define NTOK 10
#define WPAT 64
#define LTOK 5120
#define NTOKEN 163840
#define EPS 1e-5f

typedef __attribute__((ext_vector_type(8))) short bh8;
typedef __attribute__((ext_vector_type(4))) short sh4;
typedef __attribute__((ext_vector_type(4))) float fx4;

__device__ inline unsigned short f2bf(float f) {
    unsigned int u = __builtin_bit_cast(unsigned int, f);
    u += 0x7fffu + ((u >> 16) & 1u);
    return (unsigned short)(u >> 16);
}
__device__ inline float bf2f(unsigned short h) {
    return __builtin_bit_cast(float, (unsigned int)h << 16);
}

__device__ inline float wave_reduce_sum(float v) {
    #pragma unroll
    for (int off = 32; off > 0; off >>= 1) v += __shfl_xor(v, off);
    return v;
}

// ---- kernel 0: weight prep. f32 [K][N] -> bf16 MFMA-fragment order:
//      wtf[((mat*4+s)*4+ni)*8+ko][lane][j] = W[ko*32+(lane>>4)*8+j][s*64+ni*16+(lane&15)]
__global__ void prep_kernel(const float* __restrict__ w1,
                            const float* __restrict__ w2,
                            unsigned short* __restrict__ wtf) {
    int gid = blockIdx.x * 256 + threadIdx.x;   // 16384 threads, 8 shorts each
    int lane = gid & 63;
    int ko = (gid >> 6) & 7;
    int ni = (gid >> 9) & 3;
    int s  = (gid >> 11) & 3;
    int mat = gid >> 13;
    const float* src = mat ? w2 : w1;
    int col = s * 64 + ni * 16 + (lane & 15);
    int k0 = ko * 32 + (lane >> 4) * 8;
    unsigned short* dst = wtf + (size_t)gid * 8;
    #pragma unroll
    for (int j = 0; j < 8; ++j)
        dst[j] = f2bf(src[(k0 + j) * 256 + col]);
}

// ---------------- kernel 1: LN1 + window attention + residual -> x1 -----------------
// BF=1: write bf16 to x1h (workspace). BF=0: write f32 to x1f (d_out).
template<int BF>
__global__ __launch_bounds__(256) void attn_kernel(
    const float* __restrict__ x, const float* __restrict__ g1,
    const float* __restrict__ b1, const float* __restrict__ btab,
    float* __restrict__ x1f, unsigned short* __restrict__ x1h) {
    __shared__ float xs[NTOK][DIM + 8];
    __shared__ float hs[NTOK][DIM + 8];
    __shared__ float pm[NHEAD * NTOK * NTOK];

    int w = blockIdx.x;              // 0..16383
    int b = w >> 9;
    int rh = (w >> 5) & 15;
    int cw = w & 31;
    int tid = threadIdx.x;
    int lane = tid & 63;
    int wave = tid >> 6;
    long base = (long)b * LTOK + rh * (WH * WPAT) + cw * WW;

    #pragma unroll
    for (int i = 0; i < WH; ++i) {
        const float2* src = (const float2*)(x + (base + (long)i * WPAT) * DIM);
        float2 v = src[tid];
        int p = tid * 2;
        int tok = i * 2 + (p >> 8);
        int c = p & 255;
        *(float2*)&xs[tok][c] = v;
    }
    __syncthreads();

    float4 g4 = *(const float4*)(g1 + lane * 4);
    float4 b4 = *(const float4*)(b1 + lane * 4);
    for (int tok = wave; tok < NTOK; tok += 4) {
        float4 v = *(const float4*)&xs[tok][lane * 4];
        float s = v.x + v.y + v.z + v.w;
        float q = v.x * v.x + v.y * v.y + v.z * v.z + v.w * v.w;
        s = wave_reduce_sum(s);
        q = wave_reduce_sum(q);
        float mean = s * (1.0f / DIM);
        float var = q * (1.0f / DIM) - mean * mean;
        float rstd = rsqrtf(var + EPS);
        float4 h;
        h.x = (v.x - mean) * rstd * g4.x + b4.x;
        h.y = (v.y - mean) * rstd * g4.y + b4.y;
        h.z = (v.z - mean) * rstd * g4.z + b4.z;
        h.w = (v.w - mean) * rstd * g4.w + b4.w;
        *(float4*)&hs[tok][lane * 4] = h;
    }
    __syncthreads();

    const float scale = 0.17677669529663689f;   // 32^-0.5
    for (int item = tid; item < NHEAD * NTOK * NTOK; item += 256) {
        int head = item / 100;
        int rem = item - head * 100;
        int q = rem / 10;
        int k = rem - q * 10;
        float acc = 0.f;
        #pragma unroll
        for (int d = 0; d < HD; ++d)
            acc += hs[q][head * HD + d] * hs[k][head * HD + d];
        int iq = q >> 1, jq = q & 1, ik = k >> 1, jk = k & 1;
        int bidx = (iq - ik + WH - 1) * (2 * WW - 1) + (jq - jk + WW - 1);
        pm[item] = acc * scale + btab[bidx * NHEAD + head];
    }
    __syncthreads();

    if (tid < NHEAD * NTOK) {
        float* row = pm + tid * NTOK;
        float m = row[0];
        #pragma unroll
        for (int k = 1; k < NTOK; ++k) m = fmaxf(m, row[k]);
        float e[NTOK];
        float s = 0.f;
        #pragma unroll
        for (int k = 0; k < NTOK; ++k) { e[k] = __expf(row[k] - m); s += e[k]; }
        float inv = 1.0f / s;
        #pragma unroll
        for (int k = 0; k < NTOK; ++k) row[k] = e[k] * inv;
    }
    __syncthreads();

    int head = tid >> 5;
    float hv[NTOK];
    #pragma unroll
    for (int k = 0; k < NTOK; ++k) hv[k] = hs[k][tid];
    #pragma unroll
    for (int q = 0; q < NTOK; ++q) {
        const float* pr = pm + (head * NTOK + q) * NTOK;
        float acc = 0.f;
        #pragma unroll
        for (int k = 0; k < NTOK; ++k) acc += pr[k] * hv[k];
        float o = xs[q][tid] + acc;
        long l = base + (q >> 1) * WPAT + (q & 1);
        if (BF) x1h[l * DIM + tid] = f2bf(o);
        else    x1f[l * DIM + tid] = o;
    }
}

// ---------------- kernel 2 (main): bf16 x1 -> LN2 + MLP -> f32 d_out ---------------
// 512 threads / 8 waves; wave owns a 32-col N-strip. Weight bursts split in halves
// (wf[2][4]) so peak live regs ~95; __launch_bounds__(512,4) caps at 128 (no 64-cap
// heuristic spill, which cost ~71MB of scratch writes in round 7).
__global__ __launch_bounds__(512, 4) void mlp_bf_kernel(
    const unsigned short* __restrict__ x1h, float* __restrict__ out,
    const float* __restrict__ g2, const float* __restrict__ b2,
    const unsigned short* __restrict__ wtf,
    const float* __restrict__ mb1, const float* __restrict__ mb2) {
    __shared__ unsigned short As[64][DIM + 8];

    int m0 = blockIdx.x * 64;
    int tid = threadIdx.x;       // 0..511
    int lane = tid & 63;
    int wave = tid >> 6;         // 0..7
    int lr = lane & 15;
    int lk = lane >> 4;
    int n0 = wave * 32;
    int s  = wave >> 1;          // 64-col strip index in prep layout
    int nb = (wave & 1) * 2;     // ni base within strip

    const unsigned short* w1base = wtf + (size_t)(s * 4 + nb) * 8 * 512 + (size_t)lane * 8;
    const unsigned short* w2base = w1base + 65536;

    int r = tid >> 3;            // row 0..63
    int q = tid & 7;             // 32-chan segment 0..7
    const bh8* rowp = (const bh8*)(x1h + (size_t)(m0 + r) * DIM + q * 32);

    // GEMM1 weight burst A (ko 0..3): 8 coalesced dwordx4/lane, overlaps LN2
    bh8 wf[2][4];
    #pragma unroll
    for (int ni = 0; ni < 2; ++ni)
        #pragma unroll
        for (int k = 0; k < 4; ++k)
            wf[ni][k] = *(const bh8*)(w1base + (size_t)(ni * 8 + k) * 512);

    float bias1v[2];
    #pragma unroll
    for (int ni = 0; ni < 2; ++ni) bias1v[ni] = mb1[n0 + ni * 16 + lr];

    // ---- LN2: 8 threads/row, 32 chans each
    {
        bh8 xv[4];
        #pragma unroll
        for (int j = 0; j < 4; ++j) xv[j] = rowp[j];

        float sm = 0.f, sq = 0.f;
        #pragma unroll
        for (int j = 0; j < 4; ++j)
            #pragma unroll
            for (int e = 0; e < 8; ++e) {
                float f = bf2f((unsigned short)xv[j][e]);
                sm += f; sq += f * f;
            }
        sm += __shfl_xor(sm, 1); sm += __shfl_xor(sm, 2); sm += __shfl_xor(sm, 4);
        sq += __shfl_xor(sq, 1); sq += __shfl_xor(sq, 2); sq += __shfl_xor(sq, 4);
        float mean = sm * (1.0f / DIM);
        float var = sq * (1.0f / DIM) - mean * mean;
        float rstd = rsqrtf(var + EPS);

        const float4* g4p = (const float4*)g2;
        const float4* b4p = (const float4*)b2;
        #pragma unroll
        for (int j = 0; j < 4; ++j) {
            int c4 = q * 8 + j * 2;
            float4 gA = g4p[c4],     bA = b4p[c4];
            float4 gB = g4p[c4 + 1], bB = b4p[c4 + 1];
            bh8 h;
            h[0] = (short)f2bf((bf2f((unsigned short)xv[j][0]) - mean) * rstd * gA.x + bA.x);
            h[1] = (short)f2bf((bf2f((unsigned short)xv[j][1]) - mean) * rstd * gA.y + bA.y);
            h[2] = (short)f2bf((bf2f((unsigned short)xv[j][2]) - mean) * rstd * gA.z + bA.z);
            h[3] = (short)f2bf((bf2f((unsigned short)xv[j][3]) - mean) * rstd * gA.w + bA.w);
            h[4] = (short)f2bf((bf2f((unsigned short)xv[j][4]) - mean) * rstd * gB.x + bB.x);
            h[5] = (short)f2bf((bf2f((unsigned short)xv[j][5]) - mean) * rstd * gB.y + bB.y);
            h[6] = (short)f2bf((bf2f((unsigned short)xv[j][6]) - mean) * rstd * gB.z + bB.z);
            h[7] = (short)f2bf((bf2f((unsigned short)xv[j][7]) - mean) * rstd * gB.w + bB.w);
            *(bh8*)&As[r][q * 32 + j * 8] = h;
        }
    }
    __syncthreads();

    const fx4 zero = {0.f, 0.f, 0.f, 0.f};

    // ---- GEMM1, half A (ko 0..3)
    fx4 acc[4][2];
    #pragma unroll
    for (int mi = 0; mi < 4; ++mi)
        #pragma unroll
        for (int ni = 0; ni < 2; ++ni) acc[mi][ni] = zero;

    #pragma unroll
    for (int ko = 0; ko < 4; ++ko) {
        bh8 a[4];
        #pragma unroll
        for (int mi = 0; mi < 4; ++mi)
            a[mi] = *(const bh8*)&As[mi * 16 + lr][ko * 32 + lk * 8];
        #pragma unroll
        for (int mi = 0; mi < 4; ++mi)
            #pragma unroll
            for (int ni = 0; ni < 2; ++ni)
                acc[mi][ni] = __builtin_amdgcn_mfma_f32_16x16x32_bf16(a[mi], wf[ni][ko], acc[mi][ni], 0, 0, 0);
    }

    // GEMM1 weight burst B (ko 4..7)
    #pragma unroll
    for (int ni = 0; ni < 2; ++ni)
        #pragma unroll
        for (int k = 0; k < 4; ++k)
            wf[ni][k] = *(const bh8*)(w1base + (size_t)(ni * 8 + 4 + k) * 512);

    // ---- GEMM1, half B (ko 4..7)
    #pragma unroll
    for (int ko = 0; ko < 4; ++ko) {
        bh8 a[4];
        #pragma unroll
        for (int mi = 0; mi < 4; ++mi)
            a[mi] = *(const bh8*)&As[mi * 16 + lr][(ko + 4) * 32 + lk * 8];
        #pragma unroll
        for (int mi = 0; mi < 4; ++mi)
            #pragma unroll
            for (int ni = 0; ni < 2; ++ni)
                acc[mi][ni] = __builtin_amdgcn_mfma_f32_16x16x32_bf16(a[mi], wf[ni][ko], acc[mi][ni], 0, 0, 0);
    }
    __syncthreads();

    // GEMM2 weight burst A; latency hides under gelu VALU
    #pragma unroll
    for (int ni = 0; ni < 2; ++ni)
        #pragma unroll
        for (int k = 0; k < 4; ++k)
            wf[ni][k] = *(const bh8*)(w2base + (size_t)(ni * 8 + k) * 512);

    float bias2v[2];
    #pragma unroll
    for (int ni = 0; ni < 2; ++ni) bias2v[ni] = mb2[n0 + ni * 16 + lr];

    // ---- bias1 + gelu -> bf16 back into As
    #pragma unroll
    for (int mi = 0; mi < 4; ++mi)
        #pragma unroll
        for (int ni = 0; ni < 2; ++ni)
            #pragma unroll
            for (int rr = 0; rr < 4; ++rr) {
                float vv = acc[mi][ni][rr] + bias1v[ni];
                float t = 0.7978845608028654f * (vv + 0.044715f * vv * vv * vv);
                float ge = vv / (1.0f + __expf(-2.0f * t));
                As[mi * 16 + lk * 4 + rr][n0 + ni * 16 + lr] = f2bf(ge);
            }
    __syncthreads();

    // ---- GEMM2, half A
    fx4 acc2[4][2];
    #pragma unroll
    for (int mi = 0; mi < 4; ++mi)
        #pragma unroll
        for (int ni = 0; ni < 2; ++ni) acc2[mi][ni] = zero;

    #pragma unroll
    for (int ko = 0; ko < 4; ++ko) {
        bh8 a[4];
        #pragma unroll
        for (int mi = 0; mi < 4; ++mi)
            a[mi] = *(const bh8*)&As[mi * 16 + lr][ko * 32 + lk * 8];
        #pragma unroll
        for (int mi = 0; mi < 4; ++mi)
            #pragma unroll
            for (int ni = 0; ni < 2; ++ni)
                acc2[mi][ni] = __builtin_amdgcn_mfma_f32_16x16x32_bf16(a[mi], wf[ni][ko], acc2[mi][ni], 0, 0, 0);
    }

    // GEMM2 weight burst B
    #pragma unroll
    for (int ni = 0; ni < 2; ++ni)
        #pragma unroll
        for (int k = 0; k < 4; ++k)
            wf[ni][k] = *(const bh8*)(w2base + (size_t)(ni * 8 + 4 + k) * 512);

    // ---- GEMM2, half B
    #pragma unroll
    for (int ko = 0; ko < 4; ++ko) {
        bh8 a[4];
        #pragma unroll
        for (int mi = 0; mi < 4; ++mi)
            a[mi] = *(const bh8*)&As[mi * 16 + lr][(ko + 4) * 32 + lk * 8];
        #pragma unroll
        for (int mi = 0; mi < 4; ++mi)
            #pragma unroll
            for (int ni = 0; ni < 2; ++ni)
                acc2[mi][ni] = __builtin_amdgcn_mfma_f32_16x16x32_bf16(a[mi], wf[ni][ko], acc2[mi][ni], 0, 0, 0);
    }
    __syncthreads();

    // ---- stash bias2-added mlp output (bf16) in As for the coalesced epilogue
    #pragma unroll
    for (int mi = 0; mi < 4; ++mi)
        #pragma unroll
        for (int ni = 0; ni < 2; ++ni)
            #pragma unroll
            for (int rr = 0; rr < 4; ++rr)
                As[mi * 16 + lk * 4 + rr][n0 + ni * 16 + lr] = f2bf(acc2[mi][ni][rr] + bias2v[ni]);
    __syncthreads();

    // ---- epilogue: re-read x1 segment (L2-hot) + mlp_out from LDS, float4 stores
    {
        bh8 xv[4];
        #pragma unroll
        for (int j = 0; j < 4; ++j) xv[j] = rowp[j];

        float* orow = out + (size_t)(m0 + r) * DIM + q * 32;
        #pragma unroll
        for (int j = 0; j < 4; ++j) {
            bh8 mv = *(const bh8*)&As[r][q * 32 + j * 8];
            float4 o0, o1;
            o0.x = bf2f((unsigned short)xv[j][0]) + bf2f((unsigned short)mv[0]);
            o0.y = bf2f((unsigned short)xv[j][1]) + bf2f((unsigned short)mv[1]);
            o0.z = bf2f((unsigned short)xv[j][2]) + bf2f((unsigned short)mv[2]);
            o0.w = bf2f((unsigned short)xv[j][3]) + bf2f((unsigned short)mv[3]);
            o1.x = bf2f((unsigned short)xv[j][4]) + bf2f((unsigned short)mv[4]);
            o1.y = bf2f((unsigned short)xv[j][5]) + bf2f((unsigned short)mv[5]);
            o1.z = bf2f((unsigned short)xv[j][6]) + bf2f((unsigned short)mv[6]);
            o1.w = bf2f((unsigned short)xv[j][7]) + bf2f((unsigned short)mv[7]);
            *(float4*)(orow + j * 8)     = o0;
            *(float4*)(orow + j * 8 + 4) = o1;
        }
    }
}

// ---------------- kernel 2 (fallback): round-3 in-place f32 path --------------------
__global__ __launch_bounds__(256, 2) void mlp_kernel(
    float* __restrict__ xio,
    const float* __restrict__ g2, const float* __restrict__ b2,
    const unsigned short* __restrict__ wtf,
    const float* __restrict__ mb1, const float* __restrict__ mb2) {
    __shared__ unsigned short As[64][DIM + 8];

    int m0 = blockIdx.x * 64;
    int tid = threadIdx.x;
    int lane = tid & 63;
    int wave = tid >> 6;
    int lr = lane & 15;
    int lk = lane >> 4;
    int n0 = wave * 64;

    const unsigned short* w1base = wtf + (size_t)wave * 16384 + (size_t)lane * 8;
    const unsigned short* w2base = wtf + 65536 + (size_t)wave * 16384 + (size_t)lane * 8;

    int r = tid >> 2;
    int q = tid & 3;
    const float4* rowp = (const float4*)(xio + (long)(m0 + r) * DIM);
    float4 v[16];
    #pragma unroll
    for (int i = 0; i < 16; ++i) v[i] = rowp[q + 4 * i];

    bh8 wf[4][8];
    #pragma unroll
    for (int ni = 0; ni < 4; ++ni)
        #pragma unroll
        for (int ko = 0; ko < 8; ++ko)
            wf[ni][ko] = *(const bh8*)(w1base + (size_t)(ni * 8 + ko) * 512);

    float bias1v[4];
    #pragma unroll
    for (int ni = 0; ni < 4; ++ni) bias1v[ni] = mb1[n0 + ni * 16 + lr];

    {
        float s = 0.f, sq = 0.f;
        #pragma unroll
        for (int i = 0; i < 16; ++i) {
            s += v[i].x + v[i].y + v[i].z + v[i].w;
            sq += v[i].x * v[i].x + v[i].y * v[i].y + v[i].z * v[i].z + v[i].w * v[i].w;
        }
        s += __shfl_xor(s, 1);  s += __shfl_xor(s, 2);
        sq += __shfl_xor(sq, 1); sq += __shfl_xor(sq, 2);
        float mean = s * (1.0f / DIM);
        float var = sq * (1.0f / DIM) - mean * mean;
        float rstd = rsqrtf(var + EPS);

        const float4* g4p = (const float4*)g2;
        const float4* b4p = (const float4*)b2;
        #pragma unroll
        for (int i = 0; i < 16; ++i) {
            int c4 = q + 4 * i;
            float4 gg = g4p[c4];
            float4 bb = b4p[c4];
            sh4 h;
            h.x = (short)f2bf((v[i].x - mean) * rstd * gg.x + bb.x);
            h.y = (short)f2bf((v[i].y - mean) * rstd * gg.y + bb.y);
            h.z = (short)f2bf((v[i].z - mean) * rstd * gg.z + bb.z);
            h.w = (short)f2bf((v[i].w - mean) * rstd * gg.w + bb.w);
            *(sh4*)&As[r][c4 * 4] = h;
        }
    }
    __syncthreads();

    const fx4 zero = {0.f, 0.f, 0.f, 0.f};

    fx4 acc[4][4];
    #pragma unroll
    for (int mi = 0; mi < 4; ++mi)
        #pragma unroll
        for (int ni = 0; ni < 4; ++ni) acc[mi][ni] = zero;

    #pragma unroll
    for (int ko = 0; ko < 8; ++ko) {
        bh8 a[4];
        #pragma unroll
        for (int mi = 0; mi < 4; ++mi)
            a[mi] = *(const bh8*)&As[mi * 16 + lr][ko * 32 + lk * 8];
        #pragma unroll
        for (int mi = 0; mi < 4; ++mi)
            #pragma unroll
            for (int ni = 0; ni < 4; ++ni)
                acc[mi][ni] = __builtin_amdgcn_mfma_f32_16x16x32_bf16(a[mi], wf[ni][ko], acc[mi][ni], 0, 0, 0);
    }
    __syncthreads();

    #pragma unroll
    for (int ni = 0; ni < 4; ++ni)
        #pragma unroll
        for (int ko = 0; ko < 8; ++ko)
            wf[ni][ko] = *(const bh8*)(w2base + (size_t)(ni * 8 + ko) * 512);

    float bias2v[4];
    #pragma unroll
    for (int ni = 0; ni < 4; ++ni) bias2v[ni] = mb2[n0 + ni * 16 + lr];

    #pragma unroll
    for (int mi = 0; mi < 4; ++mi)
        #pragma unroll
        for (int ni = 0; ni < 4; ++ni)
            #pragma unroll
            for (int rr = 0; rr < 4; ++rr) {
                float vv = acc[mi][ni][rr] + bias1v[ni];
                float t = 0.7978845608028654f * (vv + 0.044715f * vv * vv * vv);
                float ge = vv / (1.0f + __expf(-2.0f * t));
                As[mi * 16 + lk * 4 + rr][n0 + ni * 16 + lr] = f2bf(ge);
            }
    __syncthreads();

    fx4 acc2[4][4];
    #pragma unroll
    for (int mi = 0; mi < 4; ++mi)
        #pragma unroll
        for (int ni = 0; ni < 4; ++ni) acc2[mi][ni] = zero;

    #pragma unroll
    for (int ko = 0; ko < 8; ++ko) {
        bh8 a[4];
        #pragma unroll
        for (int mi = 0; mi < 4; ++mi)
            a[mi] = *(const bh8*)&As[mi * 16 + lr][ko * 32 + lk * 8];
        #pragma unroll
        for (int mi = 0; mi < 4; ++mi)
            #pragma unroll
            for (int ni = 0; ni < 4; ++ni)
                acc2[mi][ni] = __builtin_amdgcn_mfma_f32_16x16x32_bf16(a[mi], wf[ni][ko], acc2[mi][ni], 0, 0, 0);
    }

    #pragma unroll
    for (int mi = 0; mi < 4; ++mi)
        #pragma unroll
        for (int ni = 0; ni < 4; ++ni)
            #pragma unroll
            for (int rr = 0; rr < 4; ++rr) {
                long row = m0 + mi * 16 + lk * 4 + rr;
                int col = n0 + ni * 16 + lr;
                long idx = row * DIM + col;
                xio[idx] = xio[idx] + acc2[mi][ni][rr] + bias2v[ni];
            }
}

extern "C" void kernel_launch(void* const* d_in, const int* in_sizes, int n_in,
                              void* d_out, int out_size, void* d_ws, size_t ws_size,
                              hipStream_t stream) {
    const float* x    = (const float*)d_in[0];
    const float* g1   = (const float*)d_in[1];
    const float* b1   = (const float*)d_in[2];
    const float* btab = (const float*)d_in[3];
    const float* g2   = (const float*)d_in[6];
    const float* b2   = (const float*)d_in[7];
    const float* w1   = (const float*)d_in[8];
    const float* mb1  = (const float*)d_in[9];
    const float* w2   = (const float*)d_in[10];
    const float* mb2  = (const float*)d_in[11];
    float* out = (float*)d_out;
    unsigned short* wtf = (unsigned short*)d_ws;
    unsigned short* x1h = wtf + 131072;   // after 256 KB weight area

    size_t need = 131072ull * 2 + (size_t)NTOKEN * DIM * 2;   // 256 KB + 84 MB

    prep_kernel<<<64, 256, 0, stream>>>(w1, w2, wtf);
    if (ws_size >= need) {
        attn_kernel<1><<<16384, 256, 0, stream>>>(x, g1, b1, btab, nullptr, x1h);
        mlp_bf_kernel<<<2560, 512, 0, stream>>>(x1h, out, g2, b2, wtf, mb1, mb2);
    } else {
        attn_kernel<0><<<16384, 256, 0, stream>>>(x, g1, b1, btab, out, nullptr);
        mlp_kernel<<<2560, 256, 0, stream>>>(out, g2, b2, wtf, mb1, mb2);
    }
}